// Round 4
// baseline (626.522 us; speedup 1.0000x reference)
//
#include <hip/hip_runtime.h>
#include <hip/hip_bf16.h>

#define N_NODES 100000
#define D_IN 128
#define D_H 256
#define D_E 64
#define MT 32        // nodes per GEMM block
#define SCAN_B 1024  // scan block size

typedef __attribute__((ext_vector_type(8))) short short8;
typedef __attribute__((ext_vector_type(4))) float floatx4;

__device__ inline unsigned short f2bf(float f) {
    union { float f; unsigned u; } v; v.f = f;
    unsigned r = v.u + 0x7FFF + ((v.u >> 16) & 1);
    return (unsigned short)(r >> 16);
}
__device__ inline unsigned f2bf2(float a, float b) {
    return (unsigned)f2bf(a) | ((unsigned)f2bf(b) << 16);
}
__device__ inline float2 bf2f2(unsigned v) {
    union { unsigned u; float f; } lo, hi;
    lo.u = v << 16;
    hi.u = v & 0xffff0000u;
    return make_float2(lo.f, hi.f);  // .x = lower-address bf16
}

#define MFMA16(a, b, c) __builtin_amdgcn_mfma_f32_16x16x32_bf16((a), (b), (c), 0, 0, 0)

// ---------------- weight pre-pack to bf16 ----------------
__global__ void convert_weights(const float* __restrict__ Wl1, const float* __restrict__ Wr1,
                                const float* __restrict__ Wl2, const float* __restrict__ Wr2,
                                const float* __restrict__ fc1W, const float* __restrict__ fc2W,
                                unsigned short* __restrict__ W1b, unsigned short* __restrict__ W2b,
                                unsigned short* __restrict__ F1b, unsigned short* __restrict__ F2b) {
    int idx = blockIdx.x * blockDim.x + threadIdx.x;
    if (idx < 65536) {
        int o = idx >> 8, k = idx & 255;
        float v = (k < 128) ? Wl1[o * 128 + k] : Wr1[o * 128 + (k - 128)];
        W1b[idx] = f2bf(v);
    } else if (idx < 98304) {
        int i = idx - 65536; int o = i >> 8, k = i & 255;
        float v = (o < 64) ? Wl2[o * 256 + k] : Wr2[(o - 64) * 256 + k];
        W2b[i] = f2bf(v);
    } else if (idx < 114688) {
        int i = idx - 98304;
        F1b[i] = f2bf(fc1W[i]);
    } else if (idx < 147456) {
        int i = idx - 114688;
        F2b[i] = f2bf(fc2W[i]);
    }
}

// x fp32 -> bf16 (packed pairs)
__global__ void convert_x(const float4* __restrict__ x4, uint2* __restrict__ xbf2, int total4) {
    int idx = blockIdx.x * blockDim.x + threadIdx.x;
    if (idx >= total4) return;
    float4 v = x4[idx];
    uint2 o;
    o.x = f2bf2(v.x, v.y);
    o.y = f2bf2(v.z, v.w);
    xbf2[idx] = o;
}

// ---------------- counting sort of edges by dst ----------------

__global__ void hist_kernel(const int* __restrict__ dst, int* __restrict__ degI, int E) {
    int e = blockIdx.x * blockDim.x + threadIdx.x;
    if (e >= E) return;
    atomicAdd(&degI[dst[e]], 1);
}

__global__ void scan_block(const int* __restrict__ degI, int* __restrict__ offs,
                           int* __restrict__ bsum, int N) {
    __shared__ int s[SCAN_B];
    int tid = threadIdx.x;
    int gid = blockIdx.x * SCAN_B + tid;
    int v = (gid < N) ? degI[gid] : 0;
    s[tid] = v;
    __syncthreads();
    for (int off = 1; off < SCAN_B; off <<= 1) {
        int t = (tid >= off) ? s[tid - off] : 0;
        __syncthreads();
        s[tid] += t;
        __syncthreads();
    }
    if (gid < N) offs[gid] = s[tid] - v;
    if (tid == SCAN_B - 1) bsum[blockIdx.x] = s[tid];
}

__global__ void scan_bsum(int* __restrict__ bsum, int nb) {
    __shared__ int s[128];
    int tid = threadIdx.x;
    int v = (tid < nb) ? bsum[tid] : 0;
    s[tid] = v;
    __syncthreads();
    for (int off = 1; off < 128; off <<= 1) {
        int t = (tid >= off) ? s[tid - off] : 0;
        __syncthreads();
        s[tid] += t;
        __syncthreads();
    }
    if (tid < nb) bsum[tid] = s[tid] - v;
}

__global__ void scan_add(int* __restrict__ offs, const int* __restrict__ bsum, int N) {
    int gid = blockIdx.x * SCAN_B + threadIdx.x;
    if (gid < N) offs[gid] += bsum[blockIdx.x];
}

__global__ void reorder_kernel(const int* __restrict__ src, const int* __restrict__ dst,
                               const int* __restrict__ offs, int* __restrict__ cursor,
                               int* __restrict__ srcS, int E) {
    int e = blockIdx.x * blockDim.x + threadIdx.x;
    if (e >= E) return;
    int d = dst[e];
    int pos = offs[d] + atomicAdd(&cursor[d], 1);
    srcS[pos] = src[e];
}

// ---------------- layer1: fused gather-mean + two MFMA GEMMs ----------------
// per block (32 nodes):
//   gather: mean_n = (1/deg) * sum x_bf[src]  -> LDS sA[n][0:128] (bf16)
//           x_bf[n] staged raw                -> LDS sA[n][128:256]
//   phase A: h = relu([mean|x] @ W1b^T + bl1) -> LDS sH (bf16)
//   phase B: [z2|r2] = h @ W2b^T ; z2 -> bf16 buffer, r2 -> emb region (fp32)
__global__ __launch_bounds__(256) void layer1_fused(
        const unsigned* __restrict__ xbfu,      // [N][64] packed bf16 pairs
        const int* __restrict__ srcS, const int* __restrict__ offs,
        const int* __restrict__ degI,
        const unsigned short* __restrict__ W1b, const float* __restrict__ bl1,
        const unsigned short* __restrict__ W2b,
        unsigned short* __restrict__ z2bf, float* __restrict__ embOut) {
    __shared__ unsigned short sA[MT][264];
    __shared__ unsigned short sH[MT][264];
    const int tid = threadIdx.x;
    const int node0 = blockIdx.x * MT;
    const int wave = tid >> 6, lane = tid & 63;

    // ---- gather phase: each wave handles 8 nodes; lane = feature pair ----
    for (int i = 0; i < 8; i++) {
        const int nl = wave * 8 + i;
        const int n = node0 + nl;
        const int start = offs[n], cnt = degI[n];
        const int* sp = srcS + start;
        float2 a0 = {0.f, 0.f}, a1 = {0.f, 0.f}, a2 = {0.f, 0.f}, a3 = {0.f, 0.f};
        int j = 0;
        for (; j + 4 <= cnt; j += 4) {
            unsigned v0 = xbfu[sp[j]     * 64 + lane];
            unsigned v1 = xbfu[sp[j + 1] * 64 + lane];
            unsigned v2 = xbfu[sp[j + 2] * 64 + lane];
            unsigned v3 = xbfu[sp[j + 3] * 64 + lane];
            float2 f0 = bf2f2(v0), f1 = bf2f2(v1), f2 = bf2f2(v2), f3 = bf2f2(v3);
            a0.x += f0.x; a0.y += f0.y;
            a1.x += f1.x; a1.y += f1.y;
            a2.x += f2.x; a2.y += f2.y;
            a3.x += f3.x; a3.y += f3.y;
        }
        for (; j < cnt; j++) {
            float2 f0 = bf2f2(xbfu[sp[j] * 64 + lane]);
            a0.x += f0.x; a0.y += f0.y;
        }
        float rd = 1.0f / fmaxf((float)cnt, 1.0f);
        float mx = (a0.x + a1.x + a2.x + a3.x) * rd;
        float my = (a0.y + a1.y + a2.y + a3.y) * rd;
        unsigned* rowu = (unsigned*)&sA[nl][0];
        rowu[lane]      = f2bf2(mx, my);
        rowu[64 + lane] = xbfu[n * 64 + lane];
    }
    __syncthreads();

    const int col = lane & 15, quad = lane >> 4;

    // ---- phase A: h = relu(A @ W1b^T + bl1), N=256, K=256 ----
    short8 afr[2][8];
#pragma unroll
    for (int mt = 0; mt < 2; mt++)
#pragma unroll
        for (int ks = 0; ks < 8; ks++)
            afr[mt][ks] = *(const short8*)&sA[mt * 16 + col][ks * 32 + quad * 8];

    floatx4 acc[2][4];
    const floatx4 zero = {0.f, 0.f, 0.f, 0.f};
#pragma unroll
    for (int mt = 0; mt < 2; mt++)
#pragma unroll
        for (int nt = 0; nt < 4; nt++) acc[mt][nt] = zero;

#pragma unroll
    for (int nt = 0; nt < 4; nt++) {
        const unsigned short* wrow = W1b + ((wave * 4 + nt) * 16 + col) * 256;
#pragma unroll
        for (int ks = 0; ks < 8; ks++) {
            short8 b = *(const short8*)(wrow + ks * 32 + quad * 8);
            acc[0][nt] = MFMA16(afr[0][ks], b, acc[0][nt]);
            acc[1][nt] = MFMA16(afr[1][ks], b, acc[1][nt]);
        }
    }

#pragma unroll
    for (int nt = 0; nt < 4; nt++) {
        int out = (wave * 4 + nt) * 16 + col;
        float bias = bl1[out];
#pragma unroll
        for (int mt = 0; mt < 2; mt++)
#pragma unroll
            for (int r = 0; r < 4; r++)
                sH[mt * 16 + quad * 4 + r][out] = f2bf(fmaxf(acc[mt][nt][r] + bias, 0.f));
    }
    __syncthreads();

    // ---- phase B: [z2|r2] = h @ W2b^T, N=128, K=256 ----
    short8 hfr[2][8];
#pragma unroll
    for (int mt = 0; mt < 2; mt++)
#pragma unroll
        for (int ks = 0; ks < 8; ks++)
            hfr[mt][ks] = *(const short8*)&sH[mt * 16 + col][ks * 32 + quad * 8];

    floatx4 acc2[2][2];
#pragma unroll
    for (int mt = 0; mt < 2; mt++)
#pragma unroll
        for (int nt = 0; nt < 2; nt++) acc2[mt][nt] = zero;

#pragma unroll
    for (int nt = 0; nt < 2; nt++) {
        const unsigned short* wrow = W2b + ((wave * 2 + nt) * 16 + col) * 256;
#pragma unroll
        for (int ks = 0; ks < 8; ks++) {
            short8 b = *(const short8*)(wrow + ks * 32 + quad * 8);
            acc2[0][nt] = MFMA16(hfr[0][ks], b, acc2[0][nt]);
            acc2[1][nt] = MFMA16(hfr[1][ks], b, acc2[1][nt]);
        }
    }

#pragma unroll
    for (int nt = 0; nt < 2; nt++) {
        int out = (wave * 2 + nt) * 16 + col;
#pragma unroll
        for (int mt = 0; mt < 2; mt++)
#pragma unroll
            for (int r = 0; r < 4; r++) {
                int node = node0 + mt * 16 + quad * 4 + r;
                float v = acc2[mt][nt][r];
                if (out < 64) z2bf[node * 64 + out] = f2bf(v);
                else          embOut[node * 64 + (out - 64)] = v;
            }
    }
}

// ---------------- decoder: fused gather-emb + two MFMA GEMMs ----------------
// per block (32 nodes):
//   gather: agg_n = sum z2bf[src]; emb = agg/deg + bl2 + r2 (r2 pre-stored in emb buf)
//           -> write emb (d_out) + stage bf16 in LDS sE
//   phase A: hid = relu(emb @ F1b^T + fc1b) -> LDS sH
//   phase B: recon = hid @ F2b^T + fc2b
__global__ __launch_bounds__(256) void decoder_fused(
        const unsigned* __restrict__ z2u,       // [N][32] packed bf16 pairs
        const int* __restrict__ srcS, const int* __restrict__ offs,
        const int* __restrict__ degI,
        const float* __restrict__ bl2, float* __restrict__ emb,  // in: r2, out: emb
        const unsigned short* __restrict__ F1b, const float* __restrict__ fc1b,
        const unsigned short* __restrict__ F2b, const float* __restrict__ fc2b,
        float* __restrict__ recon) {
    __shared__ unsigned short sE[MT][72];
    __shared__ unsigned short sH[MT][264];
    const int tid = threadIdx.x;
    const int node0 = blockIdx.x * MT;
    const int wave = tid >> 6, lane = tid & 63;
    const int half = lane >> 5, l32 = lane & 31;

    // ---- gather phase: wave per 8 nodes; half-waves split edges; lane pair = 2 feats ----
    for (int i = 0; i < 8; i++) {
        const int nl = wave * 8 + i;
        const int n = node0 + nl;
        const int start = offs[n], cnt = degI[n];
        const int* sp = srcS + start;
        float ax = 0.f, ay = 0.f;
        int j = 0;
        for (; j + 4 <= cnt; j += 4) {
            unsigned v0 = z2u[sp[j + half]     * 32 + l32];
            unsigned v1 = z2u[sp[j + 2 + half] * 32 + l32];
            float2 f0 = bf2f2(v0), f1 = bf2f2(v1);
            ax += f0.x + f1.x;
            ay += f0.y + f1.y;
        }
        if (j + 2 <= cnt) {
            float2 f0 = bf2f2(z2u[sp[j + half] * 32 + l32]);
            ax += f0.x; ay += f0.y;
            j += 2;
        }
        if ((cnt & 1) && half == 0) {
            float2 f0 = bf2f2(z2u[sp[cnt - 1] * 32 + l32]);
            ax += f0.x; ay += f0.y;
        }
        ax += __shfl_down(ax, 32);
        ay += __shfl_down(ay, 32);
        if (half == 0) {
            float rd = 1.0f / fmaxf((float)cnt, 1.0f);
            float2 r2v = *(const float2*)&emb[n * 64 + l32 * 2];
            float ex = ax * rd + bl2[l32 * 2]     + r2v.x;
            float ey = ay * rd + bl2[l32 * 2 + 1] + r2v.y;
            float2 ev = {ex, ey};
            *(float2*)&emb[n * 64 + l32 * 2] = ev;
            ((unsigned*)&sE[nl][0])[l32] = f2bf2(ex, ey);
        }
    }
    __syncthreads();

    const int col = lane & 15, quad = lane >> 4;

    // ---- phase A: hid = relu(emb @ F1b^T + fc1b), N=256, K=64 ----
    short8 afr[2][2];
#pragma unroll
    for (int mt = 0; mt < 2; mt++)
#pragma unroll
        for (int ks = 0; ks < 2; ks++)
            afr[mt][ks] = *(const short8*)&sE[mt * 16 + col][ks * 32 + quad * 8];

    floatx4 acc[2][4];
    const floatx4 zero = {0.f, 0.f, 0.f, 0.f};
#pragma unroll
    for (int mt = 0; mt < 2; mt++)
#pragma unroll
        for (int nt = 0; nt < 4; nt++) acc[mt][nt] = zero;

#pragma unroll
    for (int nt = 0; nt < 4; nt++) {
        const unsigned short* wrow = F1b + ((wave * 4 + nt) * 16 + col) * 64;
#pragma unroll
        for (int ks = 0; ks < 2; ks++) {
            short8 b = *(const short8*)(wrow + ks * 32 + quad * 8);
            acc[0][nt] = MFMA16(afr[0][ks], b, acc[0][nt]);
            acc[1][nt] = MFMA16(afr[1][ks], b, acc[1][nt]);
        }
    }

#pragma unroll
    for (int nt = 0; nt < 4; nt++) {
        int out = (wave * 4 + nt) * 16 + col;
        float bias = fc1b[out];
#pragma unroll
        for (int mt = 0; mt < 2; mt++)
#pragma unroll
            for (int r = 0; r < 4; r++)
                sH[mt * 16 + quad * 4 + r][out] = f2bf(fmaxf(acc[mt][nt][r] + bias, 0.f));
    }
    __syncthreads();

    // ---- phase B: recon = hid @ F2b^T + fc2b, N=128, K=256 ----
    short8 hfr[2][8];
#pragma unroll
    for (int mt = 0; mt < 2; mt++)
#pragma unroll
        for (int ks = 0; ks < 8; ks++)
            hfr[mt][ks] = *(const short8*)&sH[mt * 16 + col][ks * 32 + quad * 8];

    floatx4 acc2[2][2];
#pragma unroll
    for (int mt = 0; mt < 2; mt++)
#pragma unroll
        for (int nt = 0; nt < 2; nt++) acc2[mt][nt] = zero;

#pragma unroll
    for (int nt = 0; nt < 2; nt++) {
        const unsigned short* wrow = F2b + ((wave * 2 + nt) * 16 + col) * 256;
#pragma unroll
        for (int ks = 0; ks < 8; ks++) {
            short8 b = *(const short8*)(wrow + ks * 32 + quad * 8);
            acc2[0][nt] = MFMA16(hfr[0][ks], b, acc2[0][nt]);
            acc2[1][nt] = MFMA16(hfr[1][ks], b, acc2[1][nt]);
        }
    }

#pragma unroll
    for (int nt = 0; nt < 2; nt++) {
        int out = (wave * 2 + nt) * 16 + col;
        float bias = fc2b[out];
#pragma unroll
        for (int mt = 0; mt < 2; mt++)
#pragma unroll
            for (int r = 0; r < 4; r++) {
                int node = node0 + mt * 16 + quad * 4 + r;
                recon[node * 128 + out] = acc2[mt][nt][r] + bias;
            }
    }
}

extern "C" void kernel_launch(void* const* d_in, const int* in_sizes, int n_in,
                              void* d_out, int out_size, void* d_ws, size_t ws_size,
                              hipStream_t stream) {
    const float* x    = (const float*)d_in[0];
    const int*   ei   = (const int*)d_in[1];
    const int E = in_sizes[1] / 2;
    const int* src = ei;
    const int* dst = ei + E;
    const float* Wl1  = (const float*)d_in[2];
    const float* bl1  = (const float*)d_in[3];
    const float* Wr1  = (const float*)d_in[4];
    const float* Wl2  = (const float*)d_in[5];
    const float* bl2  = (const float*)d_in[6];
    const float* Wr2  = (const float*)d_in[7];
    const float* fc1W = (const float*)d_in[8];
    const float* fc1b = (const float*)d_in[9];
    const float* fc2W = (const float*)d_in[10];
    const float* fc2b = (const float*)d_in[11];

    float* out   = (float*)d_out;
    float* emb   = out;                           // N*64
    float* recon = out + (size_t)N_NODES * D_E;   // N*128

    // workspace layout
    char* ws = (char*)d_ws;
    unsigned short* xbf  = (unsigned short*)(ws);             // 25,600,000 B
    unsigned short* z2bf = (unsigned short*)(ws + 25600000);  // 12,800,000 B
    int* degI   = (int*)(ws + 38400000);                      //    400,000 B
    int* offs   = (int*)(ws + 38801408);                      //    400,000 B
    int* cursor = (int*)(ws + 39202816);                      //    400,000 B
    int* bsum   = (int*)(ws + 39604224);                      //        512 B
    int* srcS   = (int*)(ws + 39604736);                      //  6,400,000 B
    unsigned short* W1b = (unsigned short*)(ws + 46005248);   //    131,072 B
    unsigned short* W2b = (unsigned short*)(ws + 46136320);   //     65,536 B
    unsigned short* F1b = (unsigned short*)(ws + 46201856);   //     32,768 B
    unsigned short* F2b = (unsigned short*)(ws + 46234624);   //     65,536 B
    // end ~46.3 MB (< 84.7 MB proven in round 3)

    hipMemsetAsync(degI,   0, (size_t)N_NODES * sizeof(int), stream);
    hipMemsetAsync(cursor, 0, (size_t)N_NODES * sizeof(int), stream);

    convert_weights<<<(147456 + 255) / 256, 256, 0, stream>>>(
        Wl1, Wr1, Wl2, Wr2, fc1W, fc2W, W1b, W2b, F1b, F2b);
    convert_x<<<(N_NODES * 32 + 255) / 256, 256, 0, stream>>>(
        (const float4*)x, (uint2*)xbf, N_NODES * 32);

    // counting sort of edges by dst
    hist_kernel<<<(E + 255) / 256, 256, 0, stream>>>(dst, degI, E);
    const int nScanBlocks = (N_NODES + SCAN_B - 1) / SCAN_B;  // 98
    scan_block<<<nScanBlocks, SCAN_B, 0, stream>>>(degI, offs, bsum, N_NODES);
    scan_bsum<<<1, 128, 0, stream>>>(bsum, nScanBlocks);
    scan_add<<<nScanBlocks, SCAN_B, 0, stream>>>(offs, bsum, N_NODES);
    reorder_kernel<<<(E + 255) / 256, 256, 0, stream>>>(src, dst, offs, cursor, srcS, E);

    // layer 1 (fused gather-mean + GEMMs): z2 -> bf16, r2 -> emb buffer
    layer1_fused<<<N_NODES / MT, 256, 0, stream>>>(
        (const unsigned*)xbf, srcS, offs, degI, W1b, bl1, W2b, z2bf, emb);

    // decoder (fused gather-emb + GEMMs): emb -> d_out, recon -> d_out
    decoder_fused<<<N_NODES / MT, 256, 0, stream>>>(
        (const unsigned*)z2bf, srcS, offs, degI, bl2, emb,
        F1b, fc1b, F2b, fc2b, recon);
}

// Round 5
// 535.577 us; speedup vs baseline: 1.1698x; 1.1698x over previous
//
#include <hip/hip_runtime.h>
#include <hip/hip_bf16.h>

#define N_NODES 100000
#define D_IN 128
#define D_H 256
#define D_E 64
#define MT 32        // nodes per GEMM block
#define SCAN_B 1024  // scan block size

typedef __attribute__((ext_vector_type(8))) short short8;
typedef __attribute__((ext_vector_type(4))) float floatx4;

__device__ inline unsigned short f2bf(float f) {
    union { float f; unsigned u; } v; v.f = f;
    unsigned r = v.u + 0x7FFF + ((v.u >> 16) & 1);
    return (unsigned short)(r >> 16);
}
__device__ inline unsigned f2bf2(float a, float b) {
    return (unsigned)f2bf(a) | ((unsigned)f2bf(b) << 16);
}
__device__ inline float2 bf2f2(unsigned v) {
    union { unsigned u; float f; } lo, hi;
    lo.u = v << 16;
    hi.u = v & 0xffff0000u;
    return make_float2(lo.f, hi.f);  // .x = lower-address bf16
}

#define MFMA16(a, b, c) __builtin_amdgcn_mfma_f32_16x16x32_bf16((a), (b), (c), 0, 0, 0)

// ---------------- weight pre-pack to bf16 ----------------
__global__ void convert_weights(const float* __restrict__ Wl1, const float* __restrict__ Wr1,
                                const float* __restrict__ Wl2, const float* __restrict__ Wr2,
                                const float* __restrict__ fc1W, const float* __restrict__ fc2W,
                                unsigned short* __restrict__ W1b, unsigned short* __restrict__ W2b,
                                unsigned short* __restrict__ F1b, unsigned short* __restrict__ F2b) {
    int idx = blockIdx.x * blockDim.x + threadIdx.x;
    if (idx < 65536) {
        int o = idx >> 8, k = idx & 255;
        float v = (k < 128) ? Wl1[o * 128 + k] : Wr1[o * 128 + (k - 128)];
        W1b[idx] = f2bf(v);
    } else if (idx < 98304) {
        int i = idx - 65536; int o = i >> 8, k = i & 255;
        float v = (o < 64) ? Wl2[o * 256 + k] : Wr2[(o - 64) * 256 + k];
        W2b[i] = f2bf(v);
    } else if (idx < 114688) {
        int i = idx - 98304;
        F1b[i] = f2bf(fc1W[i]);
    } else if (idx < 147456) {
        int i = idx - 114688;
        F2b[i] = f2bf(fc2W[i]);
    }
}

// x fp32 -> bf16 (packed pairs)
__global__ void convert_x(const float4* __restrict__ x4, uint2* __restrict__ xbf2, int total4) {
    int idx = blockIdx.x * blockDim.x + threadIdx.x;
    if (idx >= total4) return;
    float4 v = x4[idx];
    uint2 o;
    o.x = f2bf2(v.x, v.y);
    o.y = f2bf2(v.z, v.w);
    xbf2[idx] = o;
}

// ---------------- counting sort of edges by dst ----------------

__global__ void hist_kernel(const int* __restrict__ dst, int* __restrict__ degI, int E) {
    int e = blockIdx.x * blockDim.x + threadIdx.x;
    if (e >= E) return;
    atomicAdd(&degI[dst[e]], 1);
}

__global__ void scan_block(const int* __restrict__ degI, int* __restrict__ offs,
                           int* __restrict__ bsum, int N) {
    __shared__ int s[SCAN_B];
    int tid = threadIdx.x;
    int gid = blockIdx.x * SCAN_B + tid;
    int v = (gid < N) ? degI[gid] : 0;
    s[tid] = v;
    __syncthreads();
    for (int off = 1; off < SCAN_B; off <<= 1) {
        int t = (tid >= off) ? s[tid - off] : 0;
        __syncthreads();
        s[tid] += t;
        __syncthreads();
    }
    if (gid < N) offs[gid] = s[tid] - v;
    if (tid == SCAN_B - 1) bsum[blockIdx.x] = s[tid];
}

__global__ void scan_bsum(int* __restrict__ bsum, int nb) {
    __shared__ int s[128];
    int tid = threadIdx.x;
    int v = (tid < nb) ? bsum[tid] : 0;
    s[tid] = v;
    __syncthreads();
    for (int off = 1; off < 128; off <<= 1) {
        int t = (tid >= off) ? s[tid - off] : 0;
        __syncthreads();
        s[tid] += t;
        __syncthreads();
    }
    if (tid < nb) bsum[tid] = s[tid] - v;
}

__global__ void scan_add(int* __restrict__ offs, const int* __restrict__ bsum, int N) {
    int gid = blockIdx.x * SCAN_B + threadIdx.x;
    if (gid < N) offs[gid] += bsum[blockIdx.x];
}

__global__ void reorder_kernel(const int* __restrict__ src, const int* __restrict__ dst,
                               const int* __restrict__ offs, int* __restrict__ cursor,
                               int* __restrict__ srcS, int E) {
    int e = blockIdx.x * blockDim.x + threadIdx.x;
    if (e >= E) return;
    int d = dst[e];
    int pos = offs[d] + atomicAdd(&cursor[d], 1);
    srcS[pos] = src[e];
}

// ---------------- gather: mean of bf16 x rows -> packed bf16 mean ----------------
// one wave per node; lane = uint = 2 features (128 feats total)
__global__ __launch_bounds__(256) void gather_mean_bf(
        const unsigned* __restrict__ xbfu, const int* __restrict__ srcS,
        const int* __restrict__ offs, const int* __restrict__ degI,
        unsigned* __restrict__ meanbf) {
    const int wave = threadIdx.x >> 6, lane = threadIdx.x & 63;
    const int n = blockIdx.x * 4 + wave;
    if (n >= N_NODES) return;
    const int start = offs[n], cnt = degI[n];
    const int* sp = srcS + start;
    float2 a0 = {0.f, 0.f}, a1 = {0.f, 0.f}, a2 = {0.f, 0.f}, a3 = {0.f, 0.f};
    float2 a4 = {0.f, 0.f}, a5 = {0.f, 0.f}, a6 = {0.f, 0.f}, a7 = {0.f, 0.f};
    int j = 0;
    for (; j + 8 <= cnt; j += 8) {
        unsigned v0 = xbfu[sp[j]     * 64 + lane];
        unsigned v1 = xbfu[sp[j + 1] * 64 + lane];
        unsigned v2 = xbfu[sp[j + 2] * 64 + lane];
        unsigned v3 = xbfu[sp[j + 3] * 64 + lane];
        unsigned v4 = xbfu[sp[j + 4] * 64 + lane];
        unsigned v5 = xbfu[sp[j + 5] * 64 + lane];
        unsigned v6 = xbfu[sp[j + 6] * 64 + lane];
        unsigned v7 = xbfu[sp[j + 7] * 64 + lane];
        float2 f0 = bf2f2(v0), f1 = bf2f2(v1), f2 = bf2f2(v2), f3 = bf2f2(v3);
        float2 f4 = bf2f2(v4), f5 = bf2f2(v5), f6 = bf2f2(v6), f7 = bf2f2(v7);
        a0.x += f0.x; a0.y += f0.y;  a1.x += f1.x; a1.y += f1.y;
        a2.x += f2.x; a2.y += f2.y;  a3.x += f3.x; a3.y += f3.y;
        a4.x += f4.x; a4.y += f4.y;  a5.x += f5.x; a5.y += f5.y;
        a6.x += f6.x; a6.y += f6.y;  a7.x += f7.x; a7.y += f7.y;
    }
    for (; j + 2 <= cnt; j += 2) {
        float2 f0 = bf2f2(xbfu[sp[j]     * 64 + lane]);
        float2 f1 = bf2f2(xbfu[sp[j + 1] * 64 + lane]);
        a0.x += f0.x; a0.y += f0.y;
        a1.x += f1.x; a1.y += f1.y;
    }
    if (j < cnt) {
        float2 f0 = bf2f2(xbfu[sp[j] * 64 + lane]);
        a0.x += f0.x; a0.y += f0.y;
    }
    float rd = 1.0f / fmaxf((float)cnt, 1.0f);
    float mx = ((a0.x + a1.x) + (a2.x + a3.x)) + ((a4.x + a5.x) + (a6.x + a7.x));
    float my = ((a0.y + a1.y) + (a2.y + a3.y)) + ((a4.y + a5.y) + (a6.y + a7.y));
    meanbf[n * 64 + lane] = f2bf2(mx * rd, my * rd);
}

// ---------------- layer1 MFMA: [mean|x] -> h -> [z2|r2] ----------------
__global__ __launch_bounds__(256) void layer1_mfma(
        const unsigned* __restrict__ xbfu, const unsigned* __restrict__ meanbf,
        const unsigned short* __restrict__ W1b, const float* __restrict__ bl1,
        const unsigned short* __restrict__ W2b,
        unsigned short* __restrict__ z2bf, float* __restrict__ embOut) {
    __shared__ unsigned short sA[MT][264];
    __shared__ unsigned short sH[MT][264];
    const int tid = threadIdx.x;
    const int node0 = blockIdx.x * MT;

    // pure-copy staging: mean -> sA[:,0:128], x -> sA[:,128:256]
    for (int i = tid; i < MT * 64; i += 256) {
        int nl = i >> 6, u = i & 63;
        unsigned* rowu = (unsigned*)&sA[nl][0];
        rowu[u]      = meanbf[(node0 + nl) * 64 + u];
        rowu[64 + u] = xbfu[(node0 + nl) * 64 + u];
    }
    __syncthreads();

    const int wave = tid >> 6, lane = tid & 63;
    const int col = lane & 15, quad = lane >> 4;

    // ---- phase A: h = relu(A @ W1b^T + bl1), N=256, K=256 ----
    short8 afr[2][8];
#pragma unroll
    for (int mt = 0; mt < 2; mt++)
#pragma unroll
        for (int ks = 0; ks < 8; ks++)
            afr[mt][ks] = *(const short8*)&sA[mt * 16 + col][ks * 32 + quad * 8];

    floatx4 acc[2][4];
    const floatx4 zero = {0.f, 0.f, 0.f, 0.f};
#pragma unroll
    for (int mt = 0; mt < 2; mt++)
#pragma unroll
        for (int nt = 0; nt < 4; nt++) acc[mt][nt] = zero;

#pragma unroll
    for (int nt = 0; nt < 4; nt++) {
        const unsigned short* wrow = W1b + ((wave * 4 + nt) * 16 + col) * 256;
#pragma unroll
        for (int ks = 0; ks < 8; ks++) {
            short8 b = *(const short8*)(wrow + ks * 32 + quad * 8);
            acc[0][nt] = MFMA16(afr[0][ks], b, acc[0][nt]);
            acc[1][nt] = MFMA16(afr[1][ks], b, acc[1][nt]);
        }
    }

#pragma unroll
    for (int nt = 0; nt < 4; nt++) {
        int out = (wave * 4 + nt) * 16 + col;
        float bias = bl1[out];
#pragma unroll
        for (int mt = 0; mt < 2; mt++)
#pragma unroll
            for (int r = 0; r < 4; r++)
                sH[mt * 16 + quad * 4 + r][out] = f2bf(fmaxf(acc[mt][nt][r] + bias, 0.f));
    }
    __syncthreads();

    // ---- phase B: [z2|r2] = h @ W2b^T, N=128, K=256 ----
    short8 hfr[2][8];
#pragma unroll
    for (int mt = 0; mt < 2; mt++)
#pragma unroll
        for (int ks = 0; ks < 8; ks++)
            hfr[mt][ks] = *(const short8*)&sH[mt * 16 + col][ks * 32 + quad * 8];

    floatx4 acc2[2][2];
#pragma unroll
    for (int mt = 0; mt < 2; mt++)
#pragma unroll
        for (int nt = 0; nt < 2; nt++) acc2[mt][nt] = zero;

#pragma unroll
    for (int nt = 0; nt < 2; nt++) {
        const unsigned short* wrow = W2b + ((wave * 2 + nt) * 16 + col) * 256;
#pragma unroll
        for (int ks = 0; ks < 8; ks++) {
            short8 b = *(const short8*)(wrow + ks * 32 + quad * 8);
            acc2[0][nt] = MFMA16(hfr[0][ks], b, acc2[0][nt]);
            acc2[1][nt] = MFMA16(hfr[1][ks], b, acc2[1][nt]);
        }
    }

#pragma unroll
    for (int nt = 0; nt < 2; nt++) {
        int out = (wave * 2 + nt) * 16 + col;
#pragma unroll
        for (int mt = 0; mt < 2; mt++)
#pragma unroll
            for (int r = 0; r < 4; r++) {
                int node = node0 + mt * 16 + quad * 4 + r;
                float v = acc2[mt][nt][r];
                if (out < 64) z2bf[node * 64 + out] = f2bf(v);
                else          embOut[node * 64 + (out - 64)] = v;
            }
    }
}

// ---------------- gather: emb = agg(z2)/deg + bl2 + r2 ----------------
// one wave per node; half-waves split edges; lane pair covers 2 feats (64 total)
// writes emb fp32 (d_out) and packed-bf16 copy for the decoder
__global__ __launch_bounds__(256) void gather_emb(
        const unsigned* __restrict__ z2u, const int* __restrict__ srcS,
        const int* __restrict__ offs, const int* __restrict__ degI,
        const float* __restrict__ bl2, float* __restrict__ emb,
        unsigned* __restrict__ embbf) {
    const int wave = threadIdx.x >> 6, lane = threadIdx.x & 63;
    const int n = blockIdx.x * 4 + wave;
    if (n >= N_NODES) return;
    const int start = offs[n], cnt = degI[n];
    const int* sp = srcS + start;
    const int half = lane >> 5, l32 = lane & 31;
    float a0x = 0.f, a0y = 0.f, a1x = 0.f, a1y = 0.f;
    float a2x = 0.f, a2y = 0.f, a3x = 0.f, a3y = 0.f;
    int j = 0;
    for (; j + 8 <= cnt; j += 8) {
        unsigned v0 = z2u[sp[j + half]     * 32 + l32];
        unsigned v1 = z2u[sp[j + 2 + half] * 32 + l32];
        unsigned v2 = z2u[sp[j + 4 + half] * 32 + l32];
        unsigned v3 = z2u[sp[j + 6 + half] * 32 + l32];
        float2 f0 = bf2f2(v0), f1 = bf2f2(v1), f2 = bf2f2(v2), f3 = bf2f2(v3);
        a0x += f0.x; a0y += f0.y;  a1x += f1.x; a1y += f1.y;
        a2x += f2.x; a2y += f2.y;  a3x += f3.x; a3y += f3.y;
    }
    for (; j + 2 <= cnt; j += 2) {
        float2 f0 = bf2f2(z2u[sp[j + half] * 32 + l32]);
        a0x += f0.x; a0y += f0.y;
    }
    if ((cnt & 1) && half == 0) {
        float2 f0 = bf2f2(z2u[sp[cnt - 1] * 32 + l32]);
        a0x += f0.x; a0y += f0.y;
    }
    float ax = (a0x + a1x) + (a2x + a3x);
    float ay = (a0y + a1y) + (a2y + a3y);
    ax += __shfl_down(ax, 32);
    ay += __shfl_down(ay, 32);
    if (half == 0) {
        float rd = 1.0f / fmaxf((float)cnt, 1.0f);
        float2 r2v = *(const float2*)&emb[n * 64 + l32 * 2];
        float ex = ax * rd + bl2[l32 * 2]     + r2v.x;
        float ey = ay * rd + bl2[l32 * 2 + 1] + r2v.y;
        float2 ev = {ex, ey};
        *(float2*)&emb[n * 64 + l32 * 2] = ev;
        embbf[n * 32 + l32] = f2bf2(ex, ey);
    }
}

// ---------------- decoder MFMA: emb -> hid -> recon ----------------
__global__ __launch_bounds__(256) void decoder_mfma(
        const unsigned* __restrict__ embbf,
        const unsigned short* __restrict__ F1b, const float* __restrict__ fc1b,
        const unsigned short* __restrict__ F2b, const float* __restrict__ fc2b,
        float* __restrict__ recon) {
    __shared__ unsigned short sE[MT][72];
    __shared__ unsigned short sH[MT][264];
    const int tid = threadIdx.x;
    const int node0 = blockIdx.x * MT;

    for (int i = tid; i < MT * 32; i += 256) {
        int nl = i >> 5, u = i & 31;
        ((unsigned*)&sE[nl][0])[u] = embbf[(node0 + nl) * 32 + u];
    }
    __syncthreads();

    const int wave = tid >> 6, lane = tid & 63;
    const int col = lane & 15, quad = lane >> 4;

    // ---- phase A: hid = relu(emb @ F1b^T + fc1b), N=256, K=64 ----
    short8 afr[2][2];
#pragma unroll
    for (int mt = 0; mt < 2; mt++)
#pragma unroll
        for (int ks = 0; ks < 2; ks++)
            afr[mt][ks] = *(const short8*)&sE[mt * 16 + col][ks * 32 + quad * 8];

    floatx4 acc[2][4];
    const floatx4 zero = {0.f, 0.f, 0.f, 0.f};
#pragma unroll
    for (int mt = 0; mt < 2; mt++)
#pragma unroll
        for (int nt = 0; nt < 4; nt++) acc[mt][nt] = zero;

#pragma unroll
    for (int nt = 0; nt < 4; nt++) {
        const unsigned short* wrow = F1b + ((wave * 4 + nt) * 16 + col) * 64;
#pragma unroll
        for (int ks = 0; ks < 2; ks++) {
            short8 b = *(const short8*)(wrow + ks * 32 + quad * 8);
            acc[0][nt] = MFMA16(afr[0][ks], b, acc[0][nt]);
            acc[1][nt] = MFMA16(afr[1][ks], b, acc[1][nt]);
        }
    }

#pragma unroll
    for (int nt = 0; nt < 4; nt++) {
        int out = (wave * 4 + nt) * 16 + col;
        float bias = fc1b[out];
#pragma unroll
        for (int mt = 0; mt < 2; mt++)
#pragma unroll
            for (int r = 0; r < 4; r++)
                sH[mt * 16 + quad * 4 + r][out] = f2bf(fmaxf(acc[mt][nt][r] + bias, 0.f));
    }
    __syncthreads();

    // ---- phase B: recon = hid @ F2b^T + fc2b, N=128, K=256 ----
    short8 hfr[2][8];
#pragma unroll
    for (int mt = 0; mt < 2; mt++)
#pragma unroll
        for (int ks = 0; ks < 8; ks++)
            hfr[mt][ks] = *(const short8*)&sH[mt * 16 + col][ks * 32 + quad * 8];

    floatx4 acc2[2][2];
#pragma unroll
    for (int mt = 0; mt < 2; mt++)
#pragma unroll
        for (int nt = 0; nt < 2; nt++) acc2[mt][nt] = zero;

#pragma unroll
    for (int nt = 0; nt < 2; nt++) {
        const unsigned short* wrow = F2b + ((wave * 2 + nt) * 16 + col) * 256;
#pragma unroll
        for (int ks = 0; ks < 8; ks++) {
            short8 b = *(const short8*)(wrow + ks * 32 + quad * 8);
            acc2[0][nt] = MFMA16(hfr[0][ks], b, acc2[0][nt]);
            acc2[1][nt] = MFMA16(hfr[1][ks], b, acc2[1][nt]);
        }
    }

#pragma unroll
    for (int nt = 0; nt < 2; nt++) {
        int out = (wave * 2 + nt) * 16 + col;
        float bias = fc2b[out];
#pragma unroll
        for (int mt = 0; mt < 2; mt++)
#pragma unroll
            for (int r = 0; r < 4; r++) {
                int node = node0 + mt * 16 + quad * 4 + r;
                recon[node * 128 + out] = acc2[mt][nt][r] + bias;
            }
    }
}

extern "C" void kernel_launch(void* const* d_in, const int* in_sizes, int n_in,
                              void* d_out, int out_size, void* d_ws, size_t ws_size,
                              hipStream_t stream) {
    const float* x    = (const float*)d_in[0];
    const int*   ei   = (const int*)d_in[1];
    const int E = in_sizes[1] / 2;
    const int* src = ei;
    const int* dst = ei + E;
    const float* Wl1  = (const float*)d_in[2];
    const float* bl1  = (const float*)d_in[3];
    const float* Wr1  = (const float*)d_in[4];
    const float* Wl2  = (const float*)d_in[5];
    const float* bl2  = (const float*)d_in[6];
    const float* Wr2  = (const float*)d_in[7];
    const float* fc1W = (const float*)d_in[8];
    const float* fc1b = (const float*)d_in[9];
    const float* fc2W = (const float*)d_in[10];
    const float* fc2b = (const float*)d_in[11];

    float* out   = (float*)d_out;
    float* emb   = out;                           // N*64
    float* recon = out + (size_t)N_NODES * D_E;   // N*128

    // workspace layout (512-aligned offsets)
    char* ws = (char*)d_ws;
    unsigned short* xbf    = (unsigned short*)(ws);             // 25,600,000 B
    unsigned*       meanbf = (unsigned*)(ws + 25600000);        // 25,600,000 B
    unsigned short* z2bf   = (unsigned short*)(ws + 51200000);  // 12,800,000 B
    unsigned*       embbf  = (unsigned*)(ws + 64000000);        // 12,800,000 B
    int* degI   = (int*)(ws + 76800000);                        //    400,000 B
    int* offs   = (int*)(ws + 77200384);                        //    400,000 B
    int* cursor = (int*)(ws + 77600768);                        //    400,000 B
    int* bsum   = (int*)(ws + 78001152);                        //        512 B
    int* srcS   = (int*)(ws + 78001664);                        //  6,400,000 B
    unsigned short* W1b = (unsigned short*)(ws + 84401664);     //    131,072 B
    unsigned short* W2b = (unsigned short*)(ws + 84532736);     //     65,536 B
    unsigned short* F1b = (unsigned short*)(ws + 84598272);     //     32,768 B
    unsigned short* F2b = (unsigned short*)(ws + 84631040);     //     65,536 B
    // end 84,696,576 B (== R3's proven footprint)

    hipMemsetAsync(degI,   0, (size_t)N_NODES * sizeof(int), stream);
    hipMemsetAsync(cursor, 0, (size_t)N_NODES * sizeof(int), stream);

    convert_weights<<<(147456 + 255) / 256, 256, 0, stream>>>(
        Wl1, Wr1, Wl2, Wr2, fc1W, fc2W, W1b, W2b, F1b, F2b);
    convert_x<<<(N_NODES * 32 + 255) / 256, 256, 0, stream>>>(
        (const float4*)x, (uint2*)xbf, N_NODES * 32);

    // counting sort of edges by dst
    hist_kernel<<<(E + 255) / 256, 256, 0, stream>>>(dst, degI, E);
    const int nScanBlocks = (N_NODES + SCAN_B - 1) / SCAN_B;  // 98
    scan_block<<<nScanBlocks, SCAN_B, 0, stream>>>(degI, offs, bsum, N_NODES);
    scan_bsum<<<1, 128, 0, stream>>>(bsum, nScanBlocks);
    scan_add<<<nScanBlocks, SCAN_B, 0, stream>>>(offs, bsum, N_NODES);
    reorder_kernel<<<(E + 255) / 256, 256, 0, stream>>>(src, dst, offs, cursor, srcS, E);

    // layer 1
    gather_mean_bf<<<(N_NODES + 3) / 4, 256, 0, stream>>>(
        (const unsigned*)xbf, srcS, offs, degI, meanbf);
    layer1_mfma<<<N_NODES / MT, 256, 0, stream>>>(
        (const unsigned*)xbf, meanbf, W1b, bl1, W2b, z2bf, emb);

    // layer 2 aggregation + emb finalize
    gather_emb<<<(N_NODES + 3) / 4, 256, 0, stream>>>(
        (const unsigned*)z2bf, srcS, offs, degI, bl2, emb, embbf);

    // decoder
    decoder_mfma<<<N_NODES / MT, 256, 0, stream>>>(
        embbf, F1b, fc1b, F2b, fc2b, recon);
}